// Round 2
// baseline (55.453 us; speedup 1.0000x reference)
//
#include <hip/hip_runtime.h>
#include <math.h>

// Chamfer distance, B=8, N=M=4096, D=3, fp32.
// dist1[n] = max(sq1[n] + min_m(sq2[m] - 2 a.b[m]), 0); mean(sqrt) both dirs.
//
// R2 design: b-point stream is WAVE-UNIFORM (all lanes iterate the same
// b-points; lanes differ in a-points) -> compiler emits s_load (scalar pipe)
// for b data; the hot loop has ZERO ds_read / global_load vector traffic.
// M split across the 8 waves of a block; min-combined via LDS at the end.

#define NPTS 4096
#define BATCH 8

// ---------------- pack: (x,y,z) -> (x,y,z,||p||^2) float4 ----------------
__global__ __launch_bounds__(256) void chamfer_pack(
    const float* __restrict__ pcs1, const float* __restrict__ pcs2,
    float4* __restrict__ packed)
{
    int g = blockIdx.x * 256 + threadIdx.x;   // 64 blocks -> g in [0,16384)
#pragma unroll
    for (int p = 0; p < 4; ++p) {
        int pt    = g * 4 + p;                // [0, 65536)
        int cloud = pt >> 15;                 // 0: pcs1, 1: pcs2
        int rem   = pt & 32767;               // b*4096 + m
        const float* src = (cloud ? pcs2 : pcs1) + (size_t)rem * 3;
        float x = src[0], y = src[1], z = src[2];
        packed[pt] = make_float4(x, y, z, fmaf(x, x, fmaf(y, y, z * z)));
    }
}

// ---------------- main: 256 blocks x 512 threads ----------------
// bid: dir = bid>>7, b = (bid>>4)&7, chunk = bid&15 (256 a-points/block).
// wave w handles b-segment [w*512, w*512+512); lane l owns a-points l*4..l*4+3.
__global__ __launch_bounds__(512, 1) void chamfer_main(
    const float4* __restrict__ packed, float* __restrict__ partials)
{
    __shared__ float red[8][256];

    const int bid   = blockIdx.x;
    const int dir   = bid >> 7;
    const int b     = (bid >> 4) & 7;
    const int chunk = bid & 15;
    const int tid   = threadIdx.x;
    const int w     = tid >> 6;
    const int l     = tid & 63;

    const float4* Apk = packed + (size_t)dir       * (BATCH * NPTS) + (size_t)b * NPTS;
    const float4* Bpk = packed + (size_t)(dir ^ 1) * (BATCH * NPTS) + (size_t)b * NPTS;

    // per-thread a-points (vector loads, once)
    const int apt = chunk * 256 + l * 4;
    float nax[4], nay[4], naz[4], sq1v[4], tmin[4];
#pragma unroll
    for (int p = 0; p < 4; ++p) {
        float4 a = Apk[apt + p];
        nax[p]  = -2.0f * a.x;
        nay[p]  = -2.0f * a.y;
        naz[p]  = -2.0f * a.z;
        sq1v[p] = a.w;
        tmin[p] = 3.4e38f;
    }

    // hot loop: wave-uniform b reads (scalar loads), 4 b-points per group,
    // software-pipelined one group ahead. Last prefetch overreads 64B into
    // the partials region of d_ws (in-bounds, values unused).
    const float4* bs = Bpk + (size_t)w * 512;
    float4 q0 = bs[0], q1 = bs[1], q2 = bs[2], q3 = bs[3];
    for (int g = 0; g < 128; ++g) {
        const float4* nx = bs + g * 4 + 4;
        float4 n0 = nx[0], n1 = nx[1], n2 = nx[2], n3 = nx[3];
#pragma unroll
        for (int p = 0; p < 4; ++p) {
            float t0 = fmaf(nax[p], q0.x, fmaf(nay[p], q0.y, fmaf(naz[p], q0.z, q0.w)));
            float t1 = fmaf(nax[p], q1.x, fmaf(nay[p], q1.y, fmaf(naz[p], q1.z, q1.w)));
            float t2 = fmaf(nax[p], q2.x, fmaf(nay[p], q2.y, fmaf(naz[p], q2.z, q2.w)));
            float t3 = fmaf(nax[p], q3.x, fmaf(nay[p], q3.y, fmaf(naz[p], q3.z, q3.w)));
            tmin[p] = fminf(fminf(tmin[p], t0), t1);   // -> v_min3
            tmin[p] = fminf(fminf(tmin[p], t2), t3);
        }
        q0 = n0; q1 = n1; q2 = n2; q3 = n3;
    }

    // min-combine the 8 wave segments via LDS
#pragma unroll
    for (int p = 0; p < 4; ++p) red[w][l * 4 + p] = tmin[p];
    __syncthreads();

    if (w == 0) {
        float s = 0.0f;
#pragma unroll
        for (int p = 0; p < 4; ++p) {
            float m = red[0][l * 4 + p];
#pragma unroll
            for (int ww = 1; ww < 8; ++ww) m = fminf(m, red[ww][l * 4 + p]);
            float d = fmaxf(sq1v[p] + m, 0.0f);        // clamp cancellation
            s += sqrtf(d);
        }
#pragma unroll
        for (int off = 1; off < 64; off <<= 1) s += __shfl_xor(s, off, 64);
        if (l == 0) partials[bid] = s;
    }
}

// ---------------- final: sum n partials, scale ----------------
__global__ __launch_bounds__(256) void chamfer_final(
    const float* __restrict__ partials, int n, float* __restrict__ out)
{
    __shared__ float ws[4];
    const int t = threadIdx.x;
    float v = 0.0f;
    for (int i = t; i < n; i += 256) v += partials[i];
#pragma unroll
    for (int off = 1; off < 64; off <<= 1) v += __shfl_xor(v, off, 64);
    if ((t & 63) == 0) ws[t >> 6] = v;
    __syncthreads();
    if (t == 0)
        out[0] = (ws[0] + ws[1] + ws[2] + ws[3]) * (1.0f / 65536.0f);
    // loss = 0.5*(sum1/32768 + sum2/32768) = (sum1+sum2)/65536
}

// ---------------- fallback (proven R1 path, needs only 2KB ws) ----------------
#define PA 4
#define SPLIT 8
#define SEGLEN (NPTS / SPLIT)
#define SEGPAD (SEGLEN + 1)
#define PTS_PER_BLOCK ((256 / SPLIT) * PA)
#define BLOCKS_PER_BN (NPTS / PTS_PER_BLOCK)

__global__ __launch_bounds__(256, 2) void chamfer_min_kernel(
    const float* __restrict__ pcs1, const float* __restrict__ pcs2,
    float* __restrict__ partials)
{
    __shared__ float4 bpts[SPLIT * SEGPAD];
    __shared__ float wavesum[4];

    const int bid   = blockIdx.x;
    const int dir   = bid >> 8;
    const int r     = bid & 255;
    const int b     = r >> 5;
    const int chunk = r & 31;

    const float* A  = (dir == 0) ? pcs1 : pcs2;
    const float* Bp = (dir == 0) ? pcs2 : pcs1;
    const float* abase = A  + (size_t)b * NPTS * 3;
    const float* bbase = Bp + (size_t)b * NPTS * 3;
    const int tid = threadIdx.x;

    for (int m = tid; m < NPTS; m += 256) {
        float x = bbase[m * 3 + 0], y = bbase[m * 3 + 1], z = bbase[m * 3 + 2];
        bpts[(m >> 9) * SEGPAD + (m & 511)] =
            make_float4(x, y, z, x * x + y * y + z * z);
    }

    const int seg = tid & 7;
    const int pg  = tid >> 3;
    const int apt = chunk * PTS_PER_BLOCK + pg * PA;

    float nax[PA], nay[PA], naz[PA], sq1[PA], tmin[PA];
#pragma unroll
    for (int p = 0; p < PA; ++p) {
        float x = abase[(apt + p) * 3 + 0], y = abase[(apt + p) * 3 + 1],
              z = abase[(apt + p) * 3 + 2];
        sq1[p] = x * x + y * y + z * z;
        nax[p] = -2.0f * x; nay[p] = -2.0f * y; naz[p] = -2.0f * z;
        tmin[p] = 3.4e38f;
    }
    __syncthreads();

    const float4* bsg = &bpts[seg * SEGPAD];
#pragma unroll 4
    for (int k = 0; k < SEGLEN; ++k) {
        float4 q = bsg[k];
#pragma unroll
        for (int p = 0; p < PA; ++p) {
            float t = fmaf(nax[p], q.x, fmaf(nay[p], q.y, fmaf(naz[p], q.z, q.w)));
            tmin[p] = fminf(tmin[p], t);
        }
    }
#pragma unroll
    for (int off = 1; off < 8; off <<= 1)
#pragma unroll
        for (int p = 0; p < PA; ++p)
            tmin[p] = fminf(tmin[p], __shfl_xor(tmin[p], off, 64));

    float s = 0.0f;
    if (seg == 0) {
#pragma unroll
        for (int p = 0; p < PA; ++p)
            s += sqrtf(fmaxf(sq1[p] + tmin[p], 0.0f));
    }
#pragma unroll
    for (int off = 1; off < 64; off <<= 1) s += __shfl_xor(s, off, 64);

    if ((tid & 63) == 0) wavesum[tid >> 6] = s;
    __syncthreads();
    if (tid == 0)
        partials[bid] = wavesum[0] + wavesum[1] + wavesum[2] + wavesum[3];
}

extern "C" void kernel_launch(void* const* d_in, const int* in_sizes, int n_in,
                              void* d_out, int out_size, void* d_ws, size_t ws_size,
                              hipStream_t stream) {
    const float* pcs1 = (const float*)d_in[0];
    const float* pcs2 = (const float*)d_in[1];
    float* out = (float*)d_out;

    const size_t packed_bytes = (size_t)2 * BATCH * NPTS * sizeof(float4); // 1 MiB

    if (ws_size >= packed_bytes + 4096) {
        float4* packed  = (float4*)d_ws;
        float* partials = (float*)((char*)d_ws + packed_bytes);
        chamfer_pack <<<dim3(64),  dim3(256), 0, stream>>>(pcs1, pcs2, packed);
        chamfer_main <<<dim3(256), dim3(512), 0, stream>>>(packed, partials);
        chamfer_final<<<dim3(1),   dim3(256), 0, stream>>>(partials, 256, out);
    } else {
        float* partials = (float*)d_ws;   // 512 floats
        chamfer_min_kernel<<<dim3(512), dim3(256), 0, stream>>>(pcs1, pcs2, partials);
        chamfer_final    <<<dim3(1),   dim3(256), 0, stream>>>(partials, 512, out);
    }
}

// Round 3
// 30.531 us; speedup vs baseline: 1.8163x; 1.8163x over previous
//
#include <hip/hip_runtime.h>
#include <math.h>

// Chamfer distance, B=8, N=M=4096, D=3, fp32.
// dist1[n] = max(sq1[n] + min_m(sq2[m] - 2 a.b[m]), 0); mean(sqrt), both dirs.
//
// R3: R1's proven LDS structure, rebalanced to be VALU-bound instead of
// LDS-bound: PA=16 a-points/thread (was 4), SPLIT=32 segments (was 8).
// Per 2 b-points: 2 ds_read_b128 + 96 FMA + 16 min3  (3.5 VALU/pair).
// LDS pipe/CU ~19.5K cyc < VALU/SIMD ~28.7K cyc -> VALU-bound ~12us.

#define NPTS 4096
#define BATCH 8
#define SPLIT 32
#define SEGLEN (NPTS / SPLIT)      // 128
#define STRIDE 129                 // float4 per segment row; pad 1 -> banks
                                   // 4*seg mod 32: 8 groups x 4 segs = 4-way
#define PA 16
#define PG (256 / SPLIT)           // 8 point-groups
#define PTS_PER_BLOCK (PG * PA)    // 128
#define CHUNKS (NPTS / PTS_PER_BLOCK)  // 32
#define NBLOCKS (2 * BATCH * CHUNKS)   // 512

__global__ __launch_bounds__(256, 2) void chamfer_main(
    const float* __restrict__ pcs1, const float* __restrict__ pcs2,
    float* __restrict__ partials)
{
    __shared__ float4 bpts[SPLIT * STRIDE];   // 66,048 B -> 2 blocks/CU
    __shared__ float wavesum[4];

    const int bid   = blockIdx.x;
    const int dir   = bid >> 8;        // 256 blocks per direction
    const int b     = (bid >> 5) & 7;
    const int chunk = bid & 31;

    const float* A  = dir ? pcs2 : pcs1;
    const float* Bp = dir ? pcs1 : pcs2;
    const float* abase = A  + (size_t)b * NPTS * 3;
    const float* bbase = Bp + (size_t)b * NPTS * 3;
    const int tid = threadIdx.x;

    // ---- stage b-cloud into LDS as (x,y,z,||b||^2) ----
    for (int m = tid; m < NPTS; m += 256) {
        float x = bbase[m * 3 + 0];
        float y = bbase[m * 3 + 1];
        float z = bbase[m * 3 + 2];
        bpts[(m >> 7) * STRIDE + (m & 127)] =
            make_float4(x, y, z, fmaf(x, x, fmaf(y, y, z * z)));
    }

    // ---- per-thread a-points (registers) ----
    const int seg = tid & 31;
    const int pg  = tid >> 5;
    const int apt = chunk * PTS_PER_BLOCK + pg * PA;

    float nax[PA], nay[PA], naz[PA], sq1[PA], tmin[PA];
#pragma unroll
    for (int p = 0; p < PA; ++p) {
        float x = abase[(apt + p) * 3 + 0];
        float y = abase[(apt + p) * 3 + 1];
        float z = abase[(apt + p) * 3 + 2];
        sq1[p]  = fmaf(x, x, fmaf(y, y, z * z));
        nax[p]  = -2.0f * x;
        nay[p]  = -2.0f * y;
        naz[p]  = -2.0f * z;
        tmin[p] = 3.4e38f;
    }
    __syncthreads();

    // ---- hot loop: 64 steps x (2 ds_read_b128 + 112 VALU) ----
    const float4* bs = &bpts[seg * STRIDE];
#pragma unroll 2
    for (int k = 0; k < SEGLEN; k += 2) {
        float4 q0 = bs[k];
        float4 q1 = bs[k + 1];
#pragma unroll
        for (int p = 0; p < PA; ++p) {
            float t0 = fmaf(nax[p], q0.x,
                       fmaf(nay[p], q0.y, fmaf(naz[p], q0.z, q0.w)));
            float t1 = fmaf(nax[p], q1.x,
                       fmaf(nay[p], q1.y, fmaf(naz[p], q1.z, q1.w)));
            tmin[p] = fminf(fminf(tmin[p], t0), t1);   // -> v_min3_f32
        }
    }

    // ---- min across 32 segments (lane bits 0..4) ----
#pragma unroll
    for (int off = 1; off < 32; off <<= 1) {
#pragma unroll
        for (int p = 0; p < PA; ++p)
            tmin[p] = fminf(tmin[p], __shfl_xor(tmin[p], off, 64));
    }

    // ---- sqrt + sum (seg==0 lanes carry, others contribute 0) ----
    float s = 0.0f;
    if (seg == 0) {
#pragma unroll
        for (int p = 0; p < PA; ++p)
            s += sqrtf(fmaxf(sq1[p] + tmin[p], 0.0f));  // clamp cancellation
    }
#pragma unroll
    for (int off = 1; off < 64; off <<= 1)
        s += __shfl_xor(s, off, 64);

    if ((tid & 63) == 0) wavesum[tid >> 6] = s;
    __syncthreads();
    if (tid == 0)
        partials[bid] = wavesum[0] + wavesum[1] + wavesum[2] + wavesum[3];
}

__global__ __launch_bounds__(256) void chamfer_final(
    const float* __restrict__ partials, int n, float* __restrict__ out)
{
    __shared__ float ws[4];
    const int t = threadIdx.x;
    float v = 0.0f;
    for (int i = t; i < n; i += 256) v += partials[i];
#pragma unroll
    for (int off = 1; off < 64; off <<= 1) v += __shfl_xor(v, off, 64);
    if ((t & 63) == 0) ws[t >> 6] = v;
    __syncthreads();
    if (t == 0)
        out[0] = (ws[0] + ws[1] + ws[2] + ws[3]) * (1.0f / 65536.0f);
    // loss = 0.5*(sum1/32768 + sum2/32768) = (sum1+sum2)/65536
}

extern "C" void kernel_launch(void* const* d_in, const int* in_sizes, int n_in,
                              void* d_out, int out_size, void* d_ws, size_t ws_size,
                              hipStream_t stream) {
    const float* pcs1 = (const float*)d_in[0];
    const float* pcs2 = (const float*)d_in[1];
    float* out      = (float*)d_out;
    float* partials = (float*)d_ws;   // NBLOCKS floats = 2 KB scratch

    chamfer_main <<<dim3(NBLOCKS), dim3(256), 0, stream>>>(pcs1, pcs2, partials);
    chamfer_final<<<dim3(1),       dim3(256), 0, stream>>>(partials, NBLOCKS, out);
}